// Round 3
// baseline (13584.576 us; speedup 1.0000x reference)
//
#include <hip/hip_runtime.h>

// ---------------- problem constants ----------------
#define S_LEN 512
#define B_SZ  64
#define E_DIM 512
#define H_DIM 512
#define K_DIM 1024
#define NWG   64
#define COLS  48          // gate-cols per WG = 6 gates * 8 h-cols
#define OUT_ALLH (S_LEN*B_SZ*H_DIM)          // 16777216
#define OUT_SH   (OUT_ALLH)                  // state_hidden offset (floats)
#define OUT_SC   (OUT_ALLH + B_SZ*H_DIM)     // state_context offset

// ---------------- ws layout (bytes) ----------------
#define O_WT    0ull
#define SZ_WT   (3072ull*1024*2)             // bf16 [3072][1024]  (row n = q*512+col)
#define O_BIAS  (O_WT + SZ_WT)
#define SZ_BIAS (3072ull*4)
#define O_HBF   (O_BIAS + SZ_BIAS)
#define SZ_HBF  (2ull*64*512*2)              // bf16 [buf][wg][row][8col] writer-major blocks
#define O_FLAGH (O_HBF + SZ_HBF)
#define SZ_FLAG (64ull*64)                   // 64 flags, 64B stride each
#define O_FLAGP (O_FLAGH + SZ_FLAG)
#define O_P     (O_FLAGP + SZ_FLAG)
#define SZ_P    (64ull*128*4)                // [wg][gate*64+row] f32, writer-major
#define O_XBF   (O_P + SZ_P)
#define SZ_XBF  (512ull*64*512*2)            // bf16 copy of embedded_tokens
#define WS_FULL (O_XBF + SZ_XBF)

// ---------------- LDS layout (bytes) ----------------
#define L_WLDS  0                // 48*1024 bf16 swizzled         = 98304
#define L_ZLDS  98304            // 64*256  bf16 swizzled         = 32768
#define L_GATES 131072           // 64*52 f32                     = 13312
#define L_CST   144384           // 64*8  f32                     = 2048
#define L_BLDS  146432           // 48 f32                        = 192
#define L_SLEN  146624           // 64 int                        = 256
#define SMEM_TOTAL 146880

typedef short bf16x8 __attribute__((ext_vector_type(8)));
typedef float f32x4  __attribute__((ext_vector_type(4)));

__device__ __forceinline__ unsigned short f2bf(float f) {
  unsigned u = __float_as_uint(f);
  u += 0x7fffu + ((u >> 16) & 1u);     // round-to-nearest-even
  return (unsigned short)(u >> 16);
}

#define ATOM_LD(p)    __hip_atomic_load((p), __ATOMIC_RELAXED, __HIP_MEMORY_SCOPE_AGENT)
#define ATOM_ST(p, v) __hip_atomic_store((p), (v), __ATOMIC_RELAXED, __HIP_MEMORY_SCOPE_AGENT)

// ---------------- prep ----------------
struct PrepArgs {
  const float* W[6]; const float* bia[6];
  const float* h0;
  unsigned short* WT; float* bias_all; unsigned short* Hbf;
  int* flagH; int* flagP;
};

__global__ void prep_kernel(PrepArgs a) {
  const int n = blockIdx.x, tid = threadIdx.x;
  if (n < 3072) {
    const int q = n >> 9, col = n & 511;
    const float* Wq = a.W[q];
    for (int k = tid; k < 1024; k += 256)
      a.WT[(size_t)n*1024 + k] = f2bf(Wq[k*512 + col]);
    if (tid == 0) a.bias_all[n] = a.bia[q][col];
  } else if (n < 3136) {
    const int r = n - 3072;                       // batch row
    for (int h = tid; h < 512; h += 256) {
      const int w = h >> 3, c = h & 7;
      // buf1 block of writer w: Hbf[(1*64 + w)*512 + r*8 + c]
      a.Hbf[(size_t)(64 + w)*512 + r*8 + c] = f2bf(a.h0[r*512 + h]);
    }
  } else {
    if (tid < 64) a.flagH[tid*16] = 0;
    else if (tid < 128) a.flagP[(tid-64)*16] = 0;
  }
}

// ---------------- convert X to bf16 ----------------
__global__ void convx_kernel(const float* __restrict__ x, unsigned short* __restrict__ xbf) {
  const size_t i = ((size_t)blockIdx.x*256 + threadIdx.x) * 4;
  float4 v = *(const float4*)(x + i);
  ushort4 r;
  r.x = f2bf(v.x); r.y = f2bf(v.y); r.z = f2bf(v.z); r.w = f2bf(v.w);
  *(ushort4*)(xbf + i) = r;
}

// ---------------- persistent recurrent kernel ----------------
struct LstmArgs {
  const float* x; const unsigned short* xbf; const float* c0; const int* slen;
  const unsigned short* WT; const float* bias_all; unsigned short* Hbf;
  int* flagH; int* flagP; float* P; float* out;
};

__launch_bounds__(256)
__global__ void lstm_kernel(LstmArgs a) {
  extern __shared__ char smem[];
  char*  wlds  = smem + L_WLDS;
  char*  zlds  = smem + L_ZLDS;
  float* gates = (float*)(smem + L_GATES);
  float* cst   = (float*)(smem + L_CST);
  float* blds  = (float*)(smem + L_BLDS);
  int*   slenl = (int*)(smem + L_SLEN);

  const int wg = blockIdx.x, tid = threadIdx.x;
  const int lane = tid & 63, wv = tid >> 6;
  const bool ux = (a.xbf != nullptr);

  // ---- one-time init: weights (swizzled), biases, seq_lengths, c0 slice ----
  for (int m = tid; m < COLS*128; m += 256) {
    const int col = m >> 7, kc = m & 127;
    const int q = col >> 3, c = col & 7;
    uint4 v = *(const uint4*)(a.WT + ((size_t)(q*512 + wg*8 + c))*1024 + kc*8);
    *(uint4*)(wlds + col*2048 + ((kc ^ (col & 7)) << 4)) = v;
  }
  if (tid < COLS) { const int q = tid >> 3, c = tid & 7; blds[tid] = a.bias_all[q*512 + wg*8 + c]; }
  if (tid < 64) slenl[tid] = a.slen[tid];
  for (int e = tid; e < 512; e += 256) { const int r = e >> 3, c = e & 7; cst[e] = a.c0[r*512 + wg*8 + c]; }
  __syncthreads();

  for (int t = 0; t < S_LEN; ++t) {
    f32x4 acc[3] = { f32x4{0,0,0,0}, f32x4{0,0,0,0}, f32x4{0,0,0,0} };

    // K split into 4 quarters: kh 0,1 = x-part (no dependency), kh 2,3 = h-part (needs flagH >= t)
    for (int kh = 0; kh < 4; ++kh) {
      if (kh == 2) {
        if (tid < 64) {
          while (ATOM_LD(&a.flagH[tid*16]) < t)
            __builtin_amdgcn_s_sleep(2);
        }
      }
      __syncthreads();

      // stage zlds quarter
      if (kh < 2) {
        #pragma unroll
        for (int j = 0; j < 8; ++j) {
          const int m = tid + j*256;
          const int row = m >> 5, kc = m & 31;
          char* dst = zlds + row*512 + ((kc ^ (row & 7)) << 4);
          if (ux) {
            const size_t off = ((size_t)t*64 + row)*512 + kh*256 + kc*8;
            *(uint4*)dst = *(const uint4*)(a.xbf + off);
          } else {
            const size_t off = ((size_t)t*64 + row)*512 + kh*256 + kc*8;
            const float* sp = a.x + off;
            float4 v0 = *(const float4*)(sp);
            float4 v1 = *(const float4*)(sp + 4);
            bf16x8 r;
            r[0]=(short)f2bf(v0.x); r[1]=(short)f2bf(v0.y); r[2]=(short)f2bf(v0.z); r[3]=(short)f2bf(v0.w);
            r[4]=(short)f2bf(v1.x); r[5]=(short)f2bf(v1.y); r[6]=(short)f2bf(v1.z); r[7]=(short)f2bf(v1.w);
            *(bf16x8*)dst = r;
          }
        }
      } else {
        // h part from writer-major blocks: Hbf[(buf*64 + w)*512 + row*8 + half*4]
        const int buf = (t+1) & 1;
        unsigned long long tmp[16];
        #pragma unroll
        for (int j = 0; j < 16; ++j) {
          const int idx = tid + j*256;                 // [0,4096)
          const int wl = idx >> 7, rem = idx & 127;    // wl: writer-local 0..31
          const int row = rem >> 1, half = rem & 1;
          const size_t off = ((size_t)(buf*64 + (kh-2)*32 + wl))*512 + row*8 + half*4;
          tmp[j] = ATOM_LD((const unsigned long long*)(a.Hbf + off));
        }
        #pragma unroll
        for (int j = 0; j < 16; ++j) {
          const int idx = tid + j*256;
          const int wl = idx >> 7, rem = idx & 127;
          const int row = rem >> 1, half = rem & 1;
          *(unsigned long long*)(zlds + row*512 + ((wl ^ (row & 7)) << 4) + half*8) = tmp[j];
        }
      }
      __syncthreads();

      // MFMA over this K-quarter: 8 k-steps x 3 n-tiles
      #pragma unroll
      for (int kt = 0; kt < 8; ++kt) {
        const int arow = wv*16 + (lane & 15);
        const int akc  = kt*4 + (lane >> 4);
        bf16x8 af = *(const bf16x8*)(zlds + arow*512 + ((akc ^ (arow & 7)) << 4));
        #pragma unroll
        for (int nt = 0; nt < 3; ++nt) {
          const int bcol = nt*16 + (lane & 15);
          const int bkc  = kh*32 + kt*4 + (lane >> 4);
          bf16x8 bfr = *(const bf16x8*)(wlds + bcol*2048 + ((bkc ^ (bcol & 7)) << 4));
          acc[nt] = __builtin_amdgcn_mfma_f32_16x16x32_bf16(af, bfr, acc[nt], 0, 0, 0);
        }
      }
    }

    // ---- dump accumulators to LDS gates [row][48] (stride 52) ----
    #pragma unroll
    for (int nt = 0; nt < 3; ++nt)
      #pragma unroll
      for (int ri = 0; ri < 4; ++ri) {
        const int row = wv*16 + (lane >> 4)*4 + ri;
        gates[row*52 + nt*16 + (lane & 15)] = acc[nt][ri];
      }
    __syncthreads();

    // ---- softmax partial sums for mf/mi; exp stored back; publish P (writer-major) ----
    if (tid < 128) {
      const int gi = tid >> 6, r = tid & 63;
      float s = 0.f;
      #pragma unroll
      for (int c = 0; c < 8; ++c) {
        float e = __expf(gates[r*52 + (4+gi)*8 + c] + blds[(4+gi)*8 + c]);
        gates[r*52 + (4+gi)*8 + c] = e;
        s += e;
      }
      ATOM_ST((unsigned*)(a.P + (size_t)wg*128 + tid), __float_as_uint(s));
    }
    asm volatile("s_waitcnt vmcnt(0)" ::: "memory");
    __syncthreads();
    if (tid == 0) ATOM_ST(&a.flagP[wg*16], t+1);
    if (tid < 64) {
      while (ATOM_LD(&a.flagP[tid*16]) < t+1)
        __builtin_amdgcn_s_sleep(2);
    }
    __syncthreads();

    // ---- prefix over WGs + local cumsum -> final mf/mi in gates ----
    if (tid < 128) {
      const int gi = tid >> 6, r = tid & 63;
      float offv = 0.f, tot = 0.f;
      #pragma unroll
      for (int w = 0; w < 64; ++w) {
        float v = __uint_as_float(ATOM_LD((const unsigned*)(a.P + (size_t)w*128 + gi*64 + r)));
        tot += v;
        if (w < wg) offv += v;
      }
      const float inv = 1.f / tot;
      float run = offv;
      #pragma unroll
      for (int c = 0; c < 8; ++c) {
        run += gates[r*52 + (4+gi)*8 + c];
        gates[r*52 + (4+gi)*8 + c] = run * inv;
      }
    }
    __syncthreads();

    // ---- elementwise update: c,h; write all_h, Hbf (writer-major), states ----
    {
      const int r = tid >> 2, cp = tid & 3, c0 = cp*2;
      const float* g = gates + r*52;
      float hv[2], cv2[2];
      #pragma unroll
      for (int u = 0; u < 2; ++u) {
        const int c = c0 + u;
        const float fp = g[c]      + blds[c];
        const float ip = g[8 + c]  + blds[8 + c];
        const float op = g[16 + c] + blds[16 + c];
        const float cp2 = g[24 + c] + blds[24 + c];
        const float mf = g[32 + c];
        const float mi = g[40 + c];
        const float ft = 1.f / (1.f + __expf(-fp));
        const float it = 1.f / (1.f + __expf(-ip));
        const float ot = 1.f / (1.f + __expf(-op));
        const float ch = tanhf(cp2);
        const float w2 = mf * mi;
        const float fh = ft * w2 + (mf - w2);
        const float ih = it * w2 + (mi - w2);
        const float cn = fh * cst[r*8 + c] + ih * ch;
        cst[r*8 + c] = cn;
        cv2[u] = cn;
        hv[u] = ot * cn;
      }
      const int col = wg*8 + c0;
      *(float2*)(a.out + (size_t)t*32768 + r*512 + col) = make_float2(hv[0], hv[1]);
      const unsigned pk = (unsigned)f2bf(hv[0]) | ((unsigned)f2bf(hv[1]) << 16);
      // writer-major: Hbf[((t&1)*64 + wg)*512 + r*8 + c0]
      ATOM_ST((unsigned*)(a.Hbf + ((size_t)((t & 1)*64 + wg))*512 + r*8 + c0), pk);
      if (t == slenl[r] - 1) {
        *(float2*)(a.out + (size_t)OUT_SH + r*512 + col) = make_float2(hv[0], hv[1]);
        *(float2*)(a.out + (size_t)OUT_SC + r*512 + col) = make_float2(cv2[0], cv2[1]);
      }
    }
    asm volatile("s_waitcnt vmcnt(0)" ::: "memory");
    __syncthreads();
    if (tid == 0) ATOM_ST(&a.flagH[wg*16], t+1);
  }
}

// ---------------- host ----------------
extern "C" void kernel_launch(void* const* d_in, const int* in_sizes, int n_in,
                              void* d_out, int out_size, void* d_ws, size_t ws_size,
                              hipStream_t stream) {
  char* ws = (char*)d_ws;

  PrepArgs pa;
  for (int q = 0; q < 6; ++q) {
    pa.W[q]   = (const float*)d_in[3 + 2*q];
    pa.bia[q] = (const float*)d_in[4 + 2*q];
  }
  pa.h0       = (const float*)d_in[1];
  pa.WT       = (unsigned short*)(ws + O_WT);
  pa.bias_all = (float*)(ws + O_BIAS);
  pa.Hbf      = (unsigned short*)(ws + O_HBF);
  pa.flagH    = (int*)(ws + O_FLAGH);
  pa.flagP    = (int*)(ws + O_FLAGP);
  prep_kernel<<<3137, 256, 0, stream>>>(pa);

  const bool ux = (ws_size >= WS_FULL);
  if (ux)
    convx_kernel<<<16384, 256, 0, stream>>>((const float*)d_in[0], (unsigned short*)(ws + O_XBF));

  LstmArgs la;
  la.x        = (const float*)d_in[0];
  la.xbf      = ux ? (const unsigned short*)(ws + O_XBF) : nullptr;
  la.c0       = (const float*)d_in[2];
  la.slen     = (const int*)d_in[15];
  la.WT       = pa.WT;
  la.bias_all = pa.bias_all;
  la.Hbf      = pa.Hbf;
  la.flagH    = pa.flagH;
  la.flagP    = pa.flagP;
  la.P        = (float*)(ws + O_P);
  la.out      = (float*)d_out;

  hipFuncSetAttribute(reinterpret_cast<const void*>(lstm_kernel),
                      hipFuncAttributeMaxDynamicSharedMemorySize, SMEM_TOTAL);
  lstm_kernel<<<NWG, 256, SMEM_TOTAL, stream>>>(la);
}

// Round 4
// 6740.573 us; speedup vs baseline: 2.0153x; 2.0153x over previous
//
#include <hip/hip_runtime.h>

// ---------------- problem constants ----------------
#define S_LEN 512
#define B_SZ  64
#define E_DIM 512
#define H_DIM 512
#define K_DIM 1024
#define NWG   64
#define COLS  48          // gate-cols per WG = 6 gates * 8 h-cols
#define OUT_ALLH (S_LEN*B_SZ*H_DIM)          // 16777216
#define OUT_SH   (OUT_ALLH)                  // state_hidden offset (floats)
#define OUT_SC   (OUT_ALLH + B_SZ*H_DIM)     // state_context offset

// ---------------- ws layout (bytes) ----------------
#define O_WT    0ull
#define SZ_WT   (3072ull*1024*2)             // bf16 [3072][1024]  (row n = q*512+col)
#define O_BIAS  (O_WT + SZ_WT)               // 6291456
#define SZ_BIAS (3072ull*4)
#define O_HBF   (O_BIAS + SZ_BIAS)           // bf16 [buf][wg][row][8col] writer-major
#define SZ_HBF  (2ull*64*512*2)
#define O_FLAGH (O_HBF + SZ_HBF)             // packed 64 ints
#define O_FLAGP (O_FLAGH + 256)
#define O_P     (O_FLAGP + 256)              // [wg][gate*64+row] f32 writer-major, 32KB
#define SZ_P    (64ull*128*4)
#define O_XBF   (O_P + SZ_P)
#define SZ_XBF  (512ull*64*512*2)            // bf16 copy of embedded_tokens
#define WS_FULL (O_XBF + SZ_XBF)

// ---------------- LDS layout (bytes) ----------------
#define L_WLDS  0                 // 48*1024 bf16 swizzled          = 98304
#define L_ZP    98304             // union: zlds 32768 / Plds 33792 = 33792
#define L_GATES 132096            // 64*53 f32                      = 13568
#define L_CST   145664            // 64*9  f32                      = 2304
#define L_BLDS  147968            // 48 f32                         = 192
#define L_SLEN  148160            // 64 int                         = 256
#define SMEM_TOTAL 148416

#define GSTR 53                   // gates row stride (floats)
#define PSTR 132                  // Plds row stride (floats)

typedef short bf16x8 __attribute__((ext_vector_type(8)));
typedef float f32x4  __attribute__((ext_vector_type(4)));

__device__ __forceinline__ unsigned short f2bf(float f) {
  unsigned u = __float_as_uint(f);
  u += 0x7fffu + ((u >> 16) & 1u);     // round-to-nearest-even
  return (unsigned short)(u >> 16);
}

#define ATOM_LD(p)    __hip_atomic_load((p), __ATOMIC_RELAXED, __HIP_MEMORY_SCOPE_AGENT)
#define ATOM_ST(p, v) __hip_atomic_store((p), (v), __ATOMIC_RELAXED, __HIP_MEMORY_SCOPE_AGENT)

// ---------------- prep ----------------
struct PrepArgs {
  const float* W[6]; const float* bia[6];
  const float* h0;
  unsigned short* WT; float* bias_all; unsigned short* Hbf;
  int* flagH; int* flagP;
};

__global__ void prep_kernel(PrepArgs a) {
  const int n = blockIdx.x, tid = threadIdx.x;
  if (n < 3072) {
    const int q = n >> 9, col = n & 511;
    const float* Wq = a.W[q];
    for (int k = tid; k < 1024; k += 256)
      a.WT[(size_t)n*1024 + k] = f2bf(Wq[k*512 + col]);
    if (tid == 0) a.bias_all[n] = a.bia[q][col];
  } else if (n < 3136) {
    const int r = n - 3072;                       // batch row
    for (int h = tid; h < 512; h += 256) {
      const int w = h >> 3, c = h & 7;
      a.Hbf[(size_t)(64 + w)*512 + r*8 + c] = f2bf(a.h0[r*512 + h]);   // buf1 = h_{-1}
    }
  } else {
    if (tid < 64) a.flagH[tid] = 0;
    else if (tid < 128) a.flagP[tid - 64] = 0;
  }
}

// ---------------- convert X to bf16 ----------------
__global__ void convx_kernel(const float* __restrict__ x, unsigned short* __restrict__ xbf) {
  const size_t i = ((size_t)blockIdx.x*256 + threadIdx.x) * 4;
  float4 v = *(const float4*)(x + i);
  ushort4 r;
  r.x = f2bf(v.x); r.y = f2bf(v.y); r.z = f2bf(v.z); r.w = f2bf(v.w);
  *(ushort4*)(xbf + i) = r;
}

// ---------------- persistent recurrent kernel ----------------
struct LstmArgs {
  const float* x; const unsigned short* xbf; const float* c0; const int* slen;
  const unsigned short* WT; const float* bias_all; unsigned short* Hbf;
  int* flagH; int* flagP; float* P; float* out;
};

__launch_bounds__(256)
__global__ void lstm_kernel(LstmArgs a) {
  extern __shared__ char smem[];
  char*  wlds  = smem + L_WLDS;
  char*  zlds  = smem + L_ZP;
  float* Plds  = (float*)(smem + L_ZP);
  float* gates = (float*)(smem + L_GATES);
  float* cst   = (float*)(smem + L_CST);
  float* blds  = (float*)(smem + L_BLDS);
  int*   slenl = (int*)(smem + L_SLEN);

  const int wg = blockIdx.x, tid = threadIdx.x;
  const int lane = tid & 63, wv = tid >> 6;
  const bool ux = (a.xbf != nullptr);

  // ---- one-time init: weights (swizzled), biases, seq_lengths, c0 slice ----
  for (int m = tid; m < COLS*128; m += 256) {
    const int col = m >> 7, kc = m & 127;
    const int q = col >> 3, c = col & 7;
    uint4 v = *(const uint4*)(a.WT + ((size_t)(q*512 + wg*8 + c))*1024 + kc*8);
    *(uint4*)(wlds + col*2048 + ((kc ^ (col & 7)) << 4)) = v;
  }
  if (tid < COLS) { const int q = tid >> 3, c = tid & 7; blds[tid] = a.bias_all[q*512 + wg*8 + c]; }
  if (tid < 64) slenl[tid] = a.slen[tid];
  for (int e = tid; e < 512; e += 256) { const int r = e >> 3, c = e & 7; cst[(e>>3)*9 + (e&7)] = a.c0[r*512 + c + 0*0 ]; }
  // fix: cst[r*9+c] = c0[r*512 + wg*8 + c]
  __syncthreads();
  for (int e = tid; e < 512; e += 256) { const int r = e >> 3, c = e & 7; cst[r*9 + c] = a.c0[r*512 + wg*8 + c]; }
  __syncthreads();

  for (int t = 0; t < S_LEN; ++t) {
    f32x4 acc[3] = { f32x4{0,0,0,0}, f32x4{0,0,0,0}, f32x4{0,0,0,0} };

    // K split into 4 quarters: kh 0,1 = x-part (no dependency), kh 2,3 = h-part (needs flagH >= t)
    for (int kh = 0; kh < 4; ++kh) {
      if (kh == 2) {
        if (tid < 64) {
          while (ATOM_LD(&a.flagH[tid]) < t)
            __builtin_amdgcn_s_sleep(1);
        }
      }
      __syncthreads();

      // stage zlds quarter
      if (kh < 2) {
        #pragma unroll
        for (int j = 0; j < 8; ++j) {
          const int m = tid + j*256;
          const int row = m >> 5, kc = m & 31;
          char* dst = zlds + row*512 + ((kc ^ (row & 7)) << 4);
          if (ux) {
            const size_t off = ((size_t)t*64 + row)*512 + kh*256 + kc*8;
            *(uint4*)dst = *(const uint4*)(a.xbf + off);
          } else {
            const size_t off = ((size_t)t*64 + row)*512 + kh*256 + kc*8;
            const float* sp = a.x + off;
            float4 v0 = *(const float4*)(sp);
            float4 v1 = *(const float4*)(sp + 4);
            bf16x8 r;
            r[0]=(short)f2bf(v0.x); r[1]=(short)f2bf(v0.y); r[2]=(short)f2bf(v0.z); r[3]=(short)f2bf(v0.w);
            r[4]=(short)f2bf(v1.x); r[5]=(short)f2bf(v1.y); r[6]=(short)f2bf(v1.z); r[7]=(short)f2bf(v1.w);
            *(bf16x8*)dst = r;
          }
        }
      } else {
        // h part from writer-major blocks via 16B L2-bypass loads
        const int buf = (t+1) & 1;
        uint4 hbuf[8];
        #pragma unroll
        for (int j = 0; j < 8; ++j) {
          const int idx = tid + j*256;                 // [0,2048): (writer-local, row)
          const int wl = idx >> 6, r = idx & 63;
          const unsigned short* src = a.Hbf + ((size_t)(buf*64 + (kh-2)*32 + wl))*512 + r*8;
          asm volatile("global_load_dwordx4 %0, %1, off sc0 sc1" : "=v"(hbuf[j]) : "v"(src));
        }
        asm volatile("s_waitcnt vmcnt(0)" ::: "memory");
        __builtin_amdgcn_sched_barrier(0);
        #pragma unroll
        for (int j = 0; j < 8; ++j) {
          const int idx = tid + j*256;
          const int wl = idx >> 6, r = idx & 63;       // kc chunk within quarter == wl
          *(uint4*)(zlds + r*512 + ((wl ^ (r & 7)) << 4)) = hbuf[j];
        }
      }
      __syncthreads();

      // MFMA over this K-quarter: 8 k-steps x 3 n-tiles
      #pragma unroll
      for (int kt = 0; kt < 8; ++kt) {
        const int arow = wv*16 + (lane & 15);
        const int akc  = kt*4 + (lane >> 4);
        bf16x8 af = *(const bf16x8*)(zlds + arow*512 + ((akc ^ (arow & 7)) << 4));
        #pragma unroll
        for (int nt = 0; nt < 3; ++nt) {
          const int bcol = nt*16 + (lane & 15);
          const int bkc  = kh*32 + kt*4 + (lane >> 4);
          bf16x8 bfr = *(const bf16x8*)(wlds + bcol*2048 + ((bkc ^ (bcol & 7)) << 4));
          acc[nt] = __builtin_amdgcn_mfma_f32_16x16x32_bf16(af, bfr, acc[nt], 0, 0, 0);
        }
      }
    }

    // ---- dump accumulators to LDS gates [row][48] (stride GSTR) ----
    #pragma unroll
    for (int nt = 0; nt < 3; ++nt)
      #pragma unroll
      for (int ri = 0; ri < 4; ++ri) {
        const int row = wv*16 + (lane >> 4)*4 + ri;
        gates[row*GSTR + nt*16 + (lane & 15)] = acc[nt][ri];
      }
    __syncthreads();

    // ---- softmax partials for mf/mi (cols 32..47); exp stored back; publish P ----
    if (tid < 128) {
      const int gi = tid >> 6, r = tid & 63;
      float s = 0.f;
      #pragma unroll
      for (int c = 0; c < 8; ++c) {
        float e = __expf(gates[r*GSTR + (4+gi)*8 + c] + blds[(4+gi)*8 + c]);
        gates[r*GSTR + (4+gi)*8 + c] = e;
        s += e;
      }
      ATOM_ST((unsigned*)(a.P + (size_t)wg*128 + tid), __float_as_uint(s));
    }
    asm volatile("s_waitcnt vmcnt(0)" ::: "memory");
    __syncthreads();
    if (tid == 0) ATOM_ST(&a.flagP[wg], t+1);

    // ---- overlap P flight: sigmoid/tanh transform of f,i,o,c (cols 0..31) ----
    #pragma unroll
    for (int j = 0; j < 8; ++j) {
      const int m2 = tid + j*256;
      const int r = m2 >> 5, c = m2 & 31;
      const float v = gates[r*GSTR + c] + blds[c];
      const float e = __expf((c < 24) ? -v : 2.f*v);
      gates[r*GSTR + c] = (c < 24) ? 1.f/(1.f+e) : (e-1.f)/(e+1.f);
    }

    if (tid < 64) {
      while (ATOM_LD(&a.flagP[tid]) < t+1)
        __builtin_amdgcn_s_sleep(1);
    }
    __syncthreads();

    // ---- stage all P (32KB) into Plds via 16B bypass loads ----
    {
      uint4 pbuf[8];
      #pragma unroll
      for (int j = 0; j < 8; ++j) {
        const int idx = tid + j*256;                 // [0,2048) 16B units
        const float* src = a.P + (size_t)idx*4;
        asm volatile("global_load_dwordx4 %0, %1, off sc0 sc1" : "=v"(pbuf[j]) : "v"(src));
      }
      asm volatile("s_waitcnt vmcnt(0)" ::: "memory");
      __builtin_amdgcn_sched_barrier(0);
      #pragma unroll
      for (int j = 0; j < 8; ++j) {
        const int idx = tid + j*256;
        const int w = idx >> 5, o = (idx & 31)*4;
        *(uint4*)((char*)Plds + ((size_t)w*PSTR + o)*4) = pbuf[j];
      }
    }
    __syncthreads();

    // ---- prefix over WGs + local cumsum -> final mf/mi in gates ----
    if (tid < 128) {
      const int gi = tid >> 6, r = tid & 63;
      float offv = 0.f, tot = 0.f;
      #pragma unroll
      for (int w = 0; w < 64; ++w) {
        const float v = Plds[w*PSTR + gi*64 + r];
        tot += v;
        if (w < wg) offv += v;
      }
      const float inv = 1.f / tot;
      float run = offv;
      #pragma unroll
      for (int c = 0; c < 8; ++c) {
        run += gates[r*GSTR + (4+gi)*8 + c];
        gates[r*GSTR + (4+gi)*8 + c] = run * inv;
      }
    }
    __syncthreads();

    // ---- elementwise update: c,h; write all_h, Hbf (writer-major), states ----
    {
      const int r = tid >> 2, cp = tid & 3, c0 = cp*2;
      const float* g = gates + r*GSTR;
      float hv[2], cv2[2];
      #pragma unroll
      for (int u = 0; u < 2; ++u) {
        const int c = c0 + u;
        const float ft = g[c];          // pre-sigmoided
        const float it = g[8 + c];
        const float ot = g[16 + c];
        const float ch = g[24 + c];     // pre-tanh'd
        const float mf = g[32 + c];
        const float mi = g[40 + c];
        const float w2 = mf * mi;
        const float fh = ft * w2 + (mf - w2);
        const float ih = it * w2 + (mi - w2);
        const float cn = fh * cst[r*9 + c] + ih * ch;
        cst[r*9 + c] = cn;
        cv2[u] = cn;
        hv[u] = ot * cn;
      }
      const int col = wg*8 + c0;
      *(float2*)(a.out + (size_t)t*32768 + r*512 + col) = make_float2(hv[0], hv[1]);
      const unsigned pk = (unsigned)f2bf(hv[0]) | ((unsigned)f2bf(hv[1]) << 16);
      ATOM_ST((unsigned*)(a.Hbf + ((size_t)((t & 1)*64 + wg))*512 + r*8 + c0), pk);
      if (t == slenl[r] - 1) {
        *(float2*)(a.out + (size_t)OUT_SH + r*512 + col) = make_float2(hv[0], hv[1]);
        *(float2*)(a.out + (size_t)OUT_SC + r*512 + col) = make_float2(cv2[0], cv2[1]);
      }
    }
    asm volatile("s_waitcnt vmcnt(0)" ::: "memory");
    __syncthreads();
    if (tid == 0) ATOM_ST(&a.flagH[wg], t+1);
  }
}

// ---------------- host ----------------
extern "C" void kernel_launch(void* const* d_in, const int* in_sizes, int n_in,
                              void* d_out, int out_size, void* d_ws, size_t ws_size,
                              hipStream_t stream) {
  char* ws = (char*)d_ws;

  PrepArgs pa;
  for (int q = 0; q < 6; ++q) {
    pa.W[q]   = (const float*)d_in[3 + 2*q];
    pa.bia[q] = (const float*)d_in[4 + 2*q];
  }
  pa.h0       = (const float*)d_in[1];
  pa.WT       = (unsigned short*)(ws + O_WT);
  pa.bias_all = (float*)(ws + O_BIAS);
  pa.Hbf      = (unsigned short*)(ws + O_HBF);
  pa.flagH    = (int*)(ws + O_FLAGH);
  pa.flagP    = (int*)(ws + O_FLAGP);
  prep_kernel<<<3137, 256, 0, stream>>>(pa);

  const bool ux = (ws_size >= WS_FULL);
  if (ux)
    convx_kernel<<<16384, 256, 0, stream>>>((const float*)d_in[0], (unsigned short*)(ws + O_XBF));

  LstmArgs la;
  la.x        = (const float*)d_in[0];
  la.xbf      = ux ? (const unsigned short*)(ws + O_XBF) : nullptr;
  la.c0       = (const float*)d_in[2];
  la.slen     = (const int*)d_in[15];
  la.WT       = pa.WT;
  la.bias_all = pa.bias_all;
  la.Hbf      = pa.Hbf;
  la.flagH    = pa.flagH;
  la.flagP    = pa.flagP;
  la.P        = (float*)(ws + O_P);
  la.out      = (float*)d_out;

  hipFuncSetAttribute(reinterpret_cast<const void*>(lstm_kernel),
                      hipFuncAttributeMaxDynamicSharedMemorySize, SMEM_TOTAL);
  lstm_kernel<<<NWG, 256, SMEM_TOTAL, stream>>>(la);
}

// Round 5
// 5990.017 us; speedup vs baseline: 2.2679x; 1.1253x over previous
//
#include <hip/hip_runtime.h>

// ---------------- problem constants ----------------
#define S_LEN 512
#define B_SZ  64
#define NWG   64
#define COLS  48
#define OUT_ALLH (S_LEN*B_SZ*512)
#define OUT_SH   (OUT_ALLH)
#define OUT_SC   (OUT_ALLH + B_SZ*512)

// ---------------- ws layout (bytes) ----------------
#define O_WT    0ull
#define SZ_WT   (3072ull*1024*2)
#define O_BIAS  (O_WT + SZ_WT)
#define SZ_BIAS (3072ull*4)
#define O_HBF   (O_BIAS + SZ_BIAS)
#define SZ_HBF  (2ull*64*512*2)
#define O_FLAGH (O_HBF + SZ_HBF)
#define O_FLAGP (O_FLAGH + 256)
#define O_P     (O_FLAGP + 256)
#define SZ_P    (64ull*128*4)
#define O_XBF   (O_P + SZ_P)
#define SZ_XBF  (512ull*64*512*2)
#define WS_FULL (O_XBF + SZ_XBF)

// ---------------- LDS layout (bytes) ----------------
#define L_WLDS  0
#define L_ZP    98304
#define L_GATES 132096
#define L_CST   145664
#define L_BLDS  147968
#define L_SLEN  148160
#define SMEM_TOTAL 148416

#define GSTR 53
#define PSTR 132

typedef short bf16x8 __attribute__((ext_vector_type(8)));
typedef float f32x4  __attribute__((ext_vector_type(4)));

__device__ __forceinline__ unsigned short f2bf(float f) {
  unsigned u = __float_as_uint(f);
  u += 0x7fffu + ((u >> 16) & 1u);
  return (unsigned short)(u >> 16);
}

#define ATOM_LD(p)    __hip_atomic_load((p), __ATOMIC_RELAXED, __HIP_MEMORY_SCOPE_AGENT)
#define ATOM_ST(p, v) __hip_atomic_store((p), (v), __ATOMIC_RELAXED, __HIP_MEMORY_SCOPE_AGENT)

struct PrepArgs {
  const float* W[6]; const float* bia[6];
  const float* h0;
  unsigned short* WT; float* bias_all; unsigned short* Hbf;
  int* flagH; int* flagP;
};

__global__ void prep_kernel(PrepArgs a) {
  const int n = blockIdx.x, tid = threadIdx.x;
  if (n < 3072) {
    const int q = n >> 9, col = n & 511;
    const float* Wq = a.W[q];
    for (int k = tid; k < 1024; k += 256)
      a.WT[(size_t)n*1024 + k] = f2bf(Wq[k*512 + col]);
    if (tid == 0) a.bias_all[n] = a.bia[q][col];
  } else if (n < 3136) {
    const int r = n - 3072;
    for (int h = tid; h < 512; h += 256) {
      const int w = h >> 3, c = h & 7;
      a.Hbf[(size_t)(64 + w)*512 + r*8 + c] = f2bf(a.h0[r*512 + h]);
    }
  } else {
    if (tid < 64) a.flagH[tid] = 0;
    else if (tid < 128) a.flagP[tid - 64] = 0;
  }
}

__global__ void convx_kernel(const float* __restrict__ x, unsigned short* __restrict__ xbf) {
  const size_t i = ((size_t)blockIdx.x*256 + threadIdx.x) * 4;
  float4 v = *(const float4*)(x + i);
  ushort4 r;
  r.x = f2bf(v.x); r.y = f2bf(v.y); r.z = f2bf(v.z); r.w = f2bf(v.w);
  *(ushort4*)(xbf + i) = r;
}

struct LstmArgs {
  const float* x; const unsigned short* xbf; const float* c0; const int* slen;
  const unsigned short* WT; const float* bias_all; unsigned short* Hbf;
  int* flagH; int* flagP; float* P; float* out;
};

__device__ __forceinline__ void mfma_quarter(const char* zlds, const char* wlds,
                                             int lane, int wv, int kh, f32x4* acc) {
  #pragma unroll
  for (int kt = 0; kt < 8; ++kt) {
    const int arow = wv*16 + (lane & 15);
    const int akc  = kt*4 + (lane >> 4);
    bf16x8 af = *(const bf16x8*)(zlds + arow*512 + (((akc + arow) & 31) << 4));
    #pragma unroll
    for (int nt = 0; nt < 3; ++nt) {
      const int bcol = nt*16 + (lane & 15);
      const int bkc  = kh*32 + kt*4 + (lane >> 4);
      bf16x8 bfr = *(const bf16x8*)(wlds + bcol*2048 + (((bkc + bcol) & 127) << 4));
      acc[nt] = __builtin_amdgcn_mfma_f32_16x16x32_bf16(af, bfr, acc[nt], 0, 0, 0);
    }
  }
}

__device__ __forceinline__ void load_x_tile(const LstmArgs& a, bool ux, int t, int tid,
                                            uint4 xq[2][8]) {
  #pragma unroll
  for (int q = 0; q < 2; ++q)
    #pragma unroll
    for (int j = 0; j < 8; ++j) {
      const int m = tid + j*256;
      const int row = m >> 5, kc = m & 31;
      const size_t off = ((size_t)t*64 + row)*512 + q*256 + kc*8;
      if (ux) {
        xq[q][j] = *(const uint4*)(a.xbf + off);
      } else {
        const float* sp = a.x + off;
        float4 v0 = *(const float4*)(sp);
        float4 v1 = *(const float4*)(sp + 4);
        unsigned w0 = (unsigned)f2bf(v0.x) | ((unsigned)f2bf(v0.y) << 16);
        unsigned w1 = (unsigned)f2bf(v0.z) | ((unsigned)f2bf(v0.w) << 16);
        unsigned w2 = (unsigned)f2bf(v1.x) | ((unsigned)f2bf(v1.y) << 16);
        unsigned w3 = (unsigned)f2bf(v1.z) | ((unsigned)f2bf(v1.w) << 16);
        xq[q][j] = uint4{w0, w1, w2, w3};
      }
    }
}

__device__ __forceinline__ void stage_x_quarter(char* zlds, int tid, const uint4* xq1) {
  #pragma unroll
  for (int j = 0; j < 8; ++j) {
    const int m = tid + j*256;
    const int row = m >> 5, kc = m & 31;
    *(uint4*)(zlds + row*512 + (((kc + row) & 31) << 4)) = xq1[j];
  }
}

__launch_bounds__(256, 1)
__global__ void lstm_kernel(LstmArgs a) {
  extern __shared__ char smem[];
  char*  wlds  = smem + L_WLDS;
  char*  zlds  = smem + L_ZP;
  float* Plds  = (float*)(smem + L_ZP);
  float* gates = (float*)(smem + L_GATES);
  float* cst   = (float*)(smem + L_CST);
  float* blds  = (float*)(smem + L_BLDS);
  int*   slenl = (int*)(smem + L_SLEN);

  const int wg = blockIdx.x, tid = threadIdx.x;
  const int lane = tid & 63, wv = tid >> 6;
  const bool ux = (a.xbf != nullptr);

  for (int m = tid; m < COLS*128; m += 256) {
    const int col = m >> 7, kc = m & 127;
    const int q = col >> 3, c = col & 7;
    uint4 v = *(const uint4*)(a.WT + ((size_t)(q*512 + wg*8 + c))*1024 + kc*8);
    *(uint4*)(wlds + col*2048 + (((kc + col) & 127) << 4)) = v;
  }
  if (tid < COLS) { const int q = tid >> 3, c = tid & 7; blds[tid] = a.bias_all[q*512 + wg*8 + c]; }
  if (tid < 64) slenl[tid] = a.slen[tid];
  for (int e = tid; e < 512; e += 256) { const int r = e >> 3, c = e & 7; cst[r*9 + c] = a.c0[r*512 + wg*8 + c]; }
  __syncthreads();

  f32x4 accC[3] = { f32x4{0,0,0,0}, f32x4{0,0,0,0}, f32x4{0,0,0,0} };
  {
    uint4 xq[2][8];
    load_x_tile(a, ux, 0, tid, xq);
    stage_x_quarter(zlds, tid, xq[0]);
    __syncthreads();
    mfma_quarter(zlds, wlds, lane, wv, 0, accC);
    __syncthreads();
    stage_x_quarter(zlds, tid, xq[1]);
    __syncthreads();
    mfma_quarter(zlds, wlds, lane, wv, 1, accC);
  }

  for (int t = 0; t < S_LEN; ++t) {
    if (tid < 64) {
      while (ATOM_LD(&a.flagH[tid]) < t)
        __builtin_amdgcn_s_sleep(1);
    }
    __syncthreads();

    const int buf = (t+1) & 1;
    {
      uint4 hb[16];
      #pragma unroll
      for (int j = 0; j < 16; ++j) {
        const int idx = tid + j*256;
        const int wl = idx >> 6, r = idx & 63;
        const unsigned short* src = a.Hbf + ((size_t)(buf*64 + wl))*512 + r*8;
        asm volatile("global_load_dwordx4 %0, %1, off sc0 sc1" : "=v"(hb[j]) : "v"(src));
      }
      asm volatile("s_waitcnt vmcnt(0)" ::: "memory");
      __builtin_amdgcn_sched_barrier(0);
      #pragma unroll
      for (int j = 0; j < 8; ++j) {
        const int idx = tid + j*256;
        const int wl = idx >> 6, r = idx & 63;
        *(uint4*)(zlds + r*512 + (((wl + r) & 31) << 4)) = hb[j];
      }
      __syncthreads();
      mfma_quarter(zlds, wlds, lane, wv, 2, accC);
      __syncthreads();
      #pragma unroll
      for (int j = 8; j < 16; ++j) {
        const int idx = tid + j*256;
        const int wl = (idx >> 6) - 32, r = idx & 63;
        *(uint4*)(zlds + r*512 + (((wl + r) & 31) << 4)) = hb[j];
      }
      __syncthreads();
      mfma_quarter(zlds, wlds, lane, wv, 3, accC);
    }

    #pragma unroll
    for (int nt = 0; nt < 3; ++nt)
      #pragma unroll
      for (int ri = 0; ri < 4; ++ri) {
        const int row = wv*16 + (lane >> 4)*4 + ri;
        gates[row*GSTR + nt*16 + (lane & 15)] = accC[nt][ri];
      }
    __syncthreads();

    const unsigned ep = (unsigned)(t & 1);

    uint4 xq[2][8];
    const int tn = t + 1;
    if (tn < S_LEN) load_x_tile(a, ux, tn, tid, xq);

    if (tid < 128) {
      const int gi = tid >> 6, r = tid & 63;
      float s = 0.f;
      #pragma unroll
      for (int c = 0; c < 8; ++c) {
        float e = __expf(gates[r*GSTR + (4+gi)*8 + c] + blds[(4+gi)*8 + c]);
        gates[r*GSTR + (4+gi)*8 + c] = e;
        s += e;
      }
      ATOM_ST((unsigned*)(a.P + (size_t)wg*128 + tid), __float_as_uint(s) | (ep << 31));
    }

    f32x4 accN[3] = { f32x4{0,0,0,0}, f32x4{0,0,0,0}, f32x4{0,0,0,0} };
    if (tn < S_LEN) {
      stage_x_quarter(zlds, tid, xq[0]);
      __syncthreads();
      mfma_quarter(zlds, wlds, lane, wv, 0, accN);
      __syncthreads();
      stage_x_quarter(zlds, tid, xq[1]);
      __syncthreads();
      mfma_quarter(zlds, wlds, lane, wv, 1, accN);
    }

    #pragma unroll
    for (int j = 0; j < 8; ++j) {
      const int m2 = tid + j*256;
      const int r = m2 >> 5, c = m2 & 31;
      const float v = gates[r*GSTR + c] + blds[c];
      const float e = __expf((c < 24) ? -v : 2.f*v);
      gates[r*GSTR + c] = (c < 24) ? 1.f/(1.f+e) : (e-1.f)/(e+1.f);
    }

    uint4 pbuf[8];
    {
      bool ok = false;
      do {
        #pragma unroll
        for (int j = 0; j < 8; ++j) {
          const int idx = tid + j*256;
          const float* src = a.P + (size_t)idx*4;
          asm volatile("global_load_dwordx4 %0, %1, off sc0 sc1" : "=v"(pbuf[j]) : "v"(src));
        }
        asm volatile("s_waitcnt vmcnt(0)" ::: "memory");
        __builtin_amdgcn_sched_barrier(0);
        unsigned agg = ep ? 0xFFFFFFFFu : 0u;
        #pragma unroll
        for (int j = 0; j < 8; ++j) {
          if (ep) agg &= (pbuf[j].x & pbuf[j].y & pbuf[j].z & pbuf[j].w);
          else    agg |= (pbuf[j].x | pbuf[j].y | pbuf[j].z | pbuf[j].w);
        }
        ok = ((agg >> 31) == ep);
        if (!ok) __builtin_amdgcn_s_sleep(1);
      } while (!ok);
    }
    __syncthreads();

    #pragma unroll
    for (int j = 0; j < 8; ++j) {
      const int idx = tid + j*256;
      const int w = idx >> 5, o = (idx & 31)*4;
      uint4 v = pbuf[j];
      v.x &= 0x7fffffffu; v.y &= 0x7fffffffu; v.z &= 0x7fffffffu; v.w &= 0x7fffffffu;
      *(uint4*)((char*)Plds + ((size_t)w*PSTR + o)*4) = v;
    }
    __syncthreads();

    if (tid < 128) {
      const int gi = tid >> 6, r = tid & 63;
      float offv = 0.f, tot = 0.f;
      #pragma unroll
      for (int w = 0; w < 64; ++w) {
        const float v = Plds[w*PSTR + gi*64 + r];
        tot += v;
        if (w < wg) offv += v;
      }
      const float inv = 1.f / tot;
      float run = offv;
      #pragma unroll
      for (int c = 0; c < 8; ++c) {
        run += gates[r*GSTR + (4+gi)*8 + c];
        gates[r*GSTR + (4+gi)*8 + c] = run * inv;
      }
    }
    __syncthreads();

    {
      const int r = tid >> 2, cp = tid & 3, c0 = cp*2;
      const float* g = gates + r*GSTR;
      float hv[2], cv2[2];
      #pragma unroll
      for (int u = 0; u < 2; ++u) {
        const int c = c0 + u;
        const float ft = g[c];
        const float it = g[8 + c];
        const float ot = g[16 + c];
        const float ch = g[24 + c];
        const float mf = g[32 + c];
        const float mi = g[40 + c];
        const float w2 = mf * mi;
        const float fh = ft * w2 + (mf - w2);
        const float ih = it * w2 + (mi - w2);
        const float cn = fh * cst[r*9 + c] + ih * ch;
        cst[r*9 + c] = cn;
        cv2[u] = cn;
        hv[u] = ot * cn;
      }
      const int col = wg*8 + c0;
      *(float2*)(a.out + (size_t)t*32768 + r*512 + col) = make_float2(hv[0], hv[1]);
      const unsigned pk = (unsigned)f2bf(hv[0]) | ((unsigned)f2bf(hv[1]) << 16);
      ATOM_ST((unsigned*)(a.Hbf + ((size_t)((t & 1)*64 + wg))*512 + r*8 + c0), pk);
      if (t == slenl[r] - 1) {
        *(float2*)(a.out + (size_t)OUT_SH + r*512 + col) = make_float2(hv[0], hv[1]);
        *(float2*)(a.out + (size_t)OUT_SC + r*512 + col) = make_float2(cv2[0], cv2[1]);
      }
    }
    asm volatile("s_waitcnt vmcnt(0)" ::: "memory");
    __syncthreads();
    if (tid == 0) ATOM_ST(&a.flagH[wg], t+1);

    accC[0] = accN[0]; accC[1] = accN[1]; accC[2] = accN[2];
  }
}

extern "C" void kernel_launch(void* const* d_in, const int* in_sizes, int n_in,
                              void* d_out, int out_size, void* d_ws, size_t ws_size,
                              hipStream_t stream) {
  char* ws = (char*)d_ws;

  PrepArgs pa;
  for (int q = 0; q < 6; ++q) {
    pa.W[q]   = (const float*)d_in[3 + 2*q];
    pa.bia[q] = (const float*)d_in[4 + 2*q];
  }
  pa.h0       = (const float*)d_in[1];
  pa.WT       = (unsigned short*)(ws + O_WT);
  pa.bias_all = (float*)(ws + O_BIAS);
  pa.Hbf      = (unsigned short*)(ws + O_HBF);
  pa.flagH    = (int*)(ws + O_FLAGH);
  pa.flagP    = (int*)(ws + O_FLAGP);
  prep_kernel<<<3137, 256, 0, stream>>>(pa);

  const bool ux = (ws_size >= WS_FULL);
  if (ux)
    convx_kernel<<<16384, 256, 0, stream>>>((const float*)d_in[0], (unsigned short*)(ws + O_XBF));

  LstmArgs la;
  la.x        = (const float*)d_in[0];
  la.xbf      = ux ? (const unsigned short*)(ws + O_XBF) : nullptr;
  la.c0       = (const float*)d_in[2];
  la.slen     = (const int*)d_in[15];
  la.WT       = pa.WT;
  la.bias_all = pa.bias_all;
  la.Hbf      = pa.Hbf;
  la.flagH    = pa.flagH;
  la.flagP    = pa.flagP;
  la.P        = (float*)(ws + O_P);
  la.out      = (float*)d_out;

  hipFuncSetAttribute(reinterpret_cast<const void*>(lstm_kernel),
                      hipFuncAttributeMaxDynamicSharedMemorySize, SMEM_TOTAL);
  lstm_kernel<<<NWG, 256, SMEM_TOTAL, stream>>>(la);
}

// Round 6
// 4047.345 us; speedup vs baseline: 3.3564x; 1.4800x over previous
//
#include <hip/hip_runtime.h>

// ---------------- problem constants ----------------
#define S_LEN 512
#define NWG   64
#define COLS  48
#define OUT_ALLH (512*64*512)
#define OUT_SH   (OUT_ALLH)
#define OUT_SC   (OUT_ALLH + 64*512)

// ---------------- ws layout (bytes) ----------------
#define O_WT    0ull
#define SZ_WT   (3072ull*1024*2)             // bf16 [3072][1024] (row n = q*512+col)
#define O_BIAS  (O_WT + SZ_WT)
#define SZ_BIAS (3072ull*4)
#define O_HBF   (O_BIAS + SZ_BIAS)           // bf16 [buf][writer][row][8col]
#define SZ_HBF  (2ull*64*512*2)
#define O_FLAGH (O_HBF + SZ_HBF)
#define O_FLAGP (O_FLAGH + 256)
#define O_P     (O_FLAGP + 256)              // [wg][gate*64+row] f32, epoch in sign bit
#define SZ_P    (64ull*128*4)
#define O_XBF   (O_P + SZ_P)
#define SZ_XBF  (512ull*64*512*2)
#define WS_FULL (O_XBF + SZ_XBF)

// ---------------- LDS layout (bytes) ----------------
#define L_WLDS  0                 // 48*1024 bf16 rot-swizzled = 98304
#define L_PLDS  98304             // 64*132 f32               = 33792
#define L_GATES 132096            // 64*53 f32                = 13568
#define L_CST   145664            // 64*9 f32                 = 2304
#define L_BLDS  147968            // 48 f32                   = 192
#define L_SLEN  148160            // 64 int                   = 256
#define L_PART  148416            // 256 float2               = 2048
#define SMEM_TOTAL 150464

#define GSTR 53
#define PSTR 132

typedef short bf16x8 __attribute__((ext_vector_type(8)));
typedef float f32x4  __attribute__((ext_vector_type(4)));

__device__ __forceinline__ unsigned short f2bf(float f) {
  unsigned u = __float_as_uint(f);
  u += 0x7fffu + ((u >> 16) & 1u);
  return (unsigned short)(u >> 16);
}

#define ATOM_LD(p)    __hip_atomic_load((p), __ATOMIC_RELAXED, __HIP_MEMORY_SCOPE_AGENT)
#define ATOM_ST(p, v) __hip_atomic_store((p), (v), __ATOMIC_RELAXED, __HIP_MEMORY_SCOPE_AGENT)

struct PrepArgs {
  const float* W[6]; const float* bia[6];
  const float* h0;
  unsigned short* WT; float* bias_all; unsigned short* Hbf;
  int* flagH; int* flagP;
};

__global__ void prep_kernel(PrepArgs a) {
  const int n = blockIdx.x, tid = threadIdx.x;
  if (n < 3072) {
    const int q = n >> 9, col = n & 511;
    const float* Wq = a.W[q];
    for (int k = tid; k < 1024; k += 256)
      a.WT[(size_t)n*1024 + k] = f2bf(Wq[k*512 + col]);
    if (tid == 0) a.bias_all[n] = a.bia[q][col];
  } else if (n < 3136) {
    const int r = n - 3072;
    for (int h = tid; h < 512; h += 256) {
      const int w = h >> 3, c = h & 7;
      a.Hbf[(size_t)(64 + w)*512 + r*8 + c] = f2bf(a.h0[r*512 + h]);  // buf1 = h_{-1}
    }
  } else {
    if (tid < 64) a.flagH[tid] = 0;
    else if (tid < 128) a.flagP[tid - 64] = 0;
  }
}

__global__ void convx_kernel(const float* __restrict__ x, unsigned short* __restrict__ xbf) {
  const size_t i = ((size_t)blockIdx.x*256 + threadIdx.x) * 4;
  float4 v = *(const float4*)(x + i);
  ushort4 r;
  r.x = f2bf(v.x); r.y = f2bf(v.y); r.z = f2bf(v.z); r.w = f2bf(v.w);
  *(ushort4*)(xbf + i) = r;
}

struct LstmArgs {
  const float* x; const unsigned short* xbf; const float* c0; const int* slen;
  const unsigned short* WT; const float* bias_all; unsigned short* Hbf;
  int* flagH; int* flagP; float* P; float* out;
};

// GEMM one K-quarter: A-fragments in registers (af[kt]), B from LDS weights.
__device__ __forceinline__ void gemm_q(const uint4* af, const char* wlds,
                                       int lane, int kh, f32x4* acc) {
  #pragma unroll
  for (int kt = 0; kt < 8; ++kt) {
    bf16x8 a = *(const bf16x8*)&af[kt];
    #pragma unroll
    for (int nt = 0; nt < 3; ++nt) {
      const int bcol = nt*16 + (lane & 15);
      const int bkc  = kh*32 + kt*4 + (lane >> 4);
      bf16x8 b = *(const bf16x8*)(wlds + bcol*2048 + (((bkc + bcol) & 127) << 4));
      acc[nt] = __builtin_amdgcn_mfma_f32_16x16x32_bf16(a, b, acc[nt], 0, 0, 0);
    }
  }
}

// Load this lane's 8 x A-fragments for quarter q of step t.
__device__ __forceinline__ void load_xf(const LstmArgs& a, bool ux, int t, int q,
                                        int arow, int lane, uint4 xf[8]) {
  #pragma unroll
  for (int kt = 0; kt < 8; ++kt) {
    const size_t off = ((size_t)t*64 + arow)*512 + (size_t)(q*32 + kt*4 + (lane >> 4))*8;
    if (ux) {
      xf[kt] = *(const uint4*)(a.xbf + off);
    } else {
      const float* sp = a.x + off;
      float4 v0 = *(const float4*)(sp);
      float4 v1 = *(const float4*)(sp + 4);
      xf[kt].x = (unsigned)f2bf(v0.x) | ((unsigned)f2bf(v0.y) << 16);
      xf[kt].y = (unsigned)f2bf(v0.z) | ((unsigned)f2bf(v0.w) << 16);
      xf[kt].z = (unsigned)f2bf(v1.x) | ((unsigned)f2bf(v1.y) << 16);
      xf[kt].w = (unsigned)f2bf(v1.z) | ((unsigned)f2bf(v1.w) << 16);
    }
  }
}

__launch_bounds__(256, 1)
__global__ void lstm_kernel(LstmArgs a) {
  extern __shared__ char smem[];
  char*  wlds  = smem + L_WLDS;
  float* Plds  = (float*)(smem + L_PLDS);
  float* gates = (float*)(smem + L_GATES);
  float* cst   = (float*)(smem + L_CST);
  float* blds  = (float*)(smem + L_BLDS);
  int*   slenl = (int*)(smem + L_SLEN);
  float* part  = (float*)(smem + L_PART);

  const int wg = blockIdx.x, tid = threadIdx.x;
  const int lane = tid & 63, wv = tid >> 6;
  const int arow = wv*16 + (lane & 15);
  const bool ux = (a.xbf != nullptr);

  // ---- one-time init: weights (rot-swizzled), biases, seq_lengths, c0 slice ----
  for (int m = tid; m < COLS*128; m += 256) {
    const int col = m >> 7, kc = m & 127;
    const int q = col >> 3, c = col & 7;
    uint4 v = *(const uint4*)(a.WT + ((size_t)(q*512 + wg*8 + c))*1024 + kc*8);
    *(uint4*)(wlds + col*2048 + (((kc + col) & 127) << 4)) = v;
  }
  if (tid < COLS) { const int q = tid >> 3, c = tid & 7; blds[tid] = a.bias_all[q*512 + wg*8 + c]; }
  if (tid < 64) slenl[tid] = a.slen[tid];
  for (int e = tid; e < 512; e += 256) { const int r = e >> 3, c = e & 7; cst[r*9 + c] = a.c0[r*512 + wg*8 + c]; }
  __syncthreads();

  // ---- prologue: x(0) GEMM into accC (no LDS staging, frags in regs) ----
  f32x4 accC[3] = { f32x4{0,0,0,0}, f32x4{0,0,0,0}, f32x4{0,0,0,0} };
  {
    uint4 xf[8];
    load_xf(a, ux, 0, 0, arow, lane, xf);
    gemm_q(xf, wlds, lane, 0, accC);
    load_xf(a, ux, 0, 1, arow, lane, xf);
    gemm_q(xf, wlds, lane, 1, accC);
  }

  for (int t = 0; t < S_LEN; ++t) {
    // ---- 1. wait for h(t-1) from all WGs ----
    if (tid < 64) {
      while (ATOM_LD(&a.flagH[tid]) < t)
        __builtin_amdgcn_s_sleep(1);
    }
    __syncthreads();

    // ---- 2. direct-to-register h fragments; GEMM kh2 overlaps second half ----
    const int buf = (t+1) & 1;
    {
      uint4 hf[16];
      #pragma unroll
      for (int j = 0; j < 16; ++j) {
        const int wl = (j & 7)*4 + (lane >> 4) + ((j >> 3) << 5);
        const unsigned short* src = a.Hbf + ((size_t)(buf*64 + wl))*512 + (size_t)arow*8;
        asm volatile("global_load_dwordx4 %0, %1, off sc0 sc1" : "=v"(hf[j]) : "v"(src));
      }
      asm volatile("s_waitcnt vmcnt(8)" ::: "memory");
      __builtin_amdgcn_sched_barrier(0);
      gemm_q(&hf[0], wlds, lane, 2, accC);
      asm volatile("s_waitcnt vmcnt(0)" ::: "memory");
      __builtin_amdgcn_sched_barrier(0);
      gemm_q(&hf[8], wlds, lane, 3, accC);
    }

    // ---- 3. dump accC -> gates [row][48] ----
    #pragma unroll
    for (int nt = 0; nt < 3; ++nt)
      #pragma unroll
      for (int ri = 0; ri < 4; ++ri) {
        const int row = wv*16 + (lane >> 4)*4 + ri;
        gates[row*GSTR + nt*16 + (lane & 15)] = accC[nt][ri];
      }
    __syncthreads();

    const unsigned ep = (unsigned)(t & 1);
    const int tn = t + 1;

    // ---- 4. softmax partials for mf/mi; publish P with epoch sign ----
    if (tid < 128) {
      const int gi = tid >> 6, r = tid & 63;
      float s = 0.f;
      #pragma unroll
      for (int c = 0; c < 8; ++c) {
        float e = __expf(gates[r*GSTR + (4+gi)*8 + c] + blds[(4+gi)*8 + c]);
        gates[r*GSTR + (4+gi)*8 + c] = e;
        s += e;
      }
      ATOM_ST((unsigned*)(a.P + (size_t)wg*128 + tid), __float_as_uint(s) | (ep << 31));
    }

    // ---- 5. x(t+1) quarter 0 GEMM (covers P flight) ----
    f32x4 accN[3] = { f32x4{0,0,0,0}, f32x4{0,0,0,0}, f32x4{0,0,0,0} };
    uint4 xf[8];
    if (tn < S_LEN) {
      load_xf(a, ux, tn, 0, arow, lane, xf);
      gemm_q(xf, wlds, lane, 0, accN);
    }

    // ---- 6. sigmoid/tanh transform of f,i,o,c (cols 0..31) ----
    #pragma unroll
    for (int j = 0; j < 8; ++j) {
      const int m2 = tid + j*256;
      const int r = m2 >> 5, c = m2 & 31;
      const float v = gates[r*GSTR + c] + blds[c];
      const float e = __expf((c < 24) ? -v : 2.f*v);
      gates[r*GSTR + c] = (c < 24) ? 1.f/(1.f+e) : (e-1.f)/(e+1.f);
    }

    // ---- 7. self-validating P poll (sign == epoch on all 32 values) ----
    uint4 pbuf[8];
    {
      bool ok = false;
      do {
        #pragma unroll
        for (int j = 0; j < 8; ++j) {
          const int idx = tid + j*256;
          const float* src = a.P + (size_t)idx*4;
          asm volatile("global_load_dwordx4 %0, %1, off sc0 sc1" : "=v"(pbuf[j]) : "v"(src));
        }
        asm volatile("s_waitcnt vmcnt(0)" ::: "memory");
        __builtin_amdgcn_sched_barrier(0);
        unsigned agg = ep ? 0xFFFFFFFFu : 0u;
        #pragma unroll
        for (int j = 0; j < 8; ++j) {
          if (ep) agg &= (pbuf[j].x & pbuf[j].y & pbuf[j].z & pbuf[j].w);
          else    agg |= (pbuf[j].x | pbuf[j].y | pbuf[j].z | pbuf[j].w);
        }
        ok = ((agg >> 31) == ep);
        if (!ok) __builtin_amdgcn_s_sleep(1);
      } while (!ok);
    }

    // ---- stage P into Plds ----
    #pragma unroll
    for (int j = 0; j < 8; ++j) {
      const int idx = tid + j*256;
      const int w = idx >> 5, o = (idx & 31)*4;
      *(uint4*)((char*)Plds + ((size_t)w*PSTR + o)*4) = pbuf[j];
    }
    __syncthreads();

    // ---- 8. two-level prefix over WGs + local cumsum ----
    {
      const int p = tid >> 1, half = tid & 1;
      const int gi = p >> 6, r = p & 63;
      float tot = 0.f, offv = 0.f;
      #pragma unroll
      for (int i = 0; i < 32; ++i) {
        const int w = half*32 + i;
        const float v = __builtin_fabsf(Plds[w*PSTR + gi*64 + r]);
        tot += v;
        if (w < wg) offv += v;
      }
      *(float2*)(part + tid*2) = make_float2(tot, offv);
    }
    __syncthreads();
    if (tid < 128) {
      const int gi = tid >> 6, r = tid & 63;
      float4 pp = *(const float4*)(part + tid*4);      // (tot0,off0,tot1,off1)
      const float inv = 1.f / (pp.x + pp.z);
      float run = pp.y + pp.w;
      #pragma unroll
      for (int c = 0; c < 8; ++c) {
        run += gates[r*GSTR + (4+gi)*8 + c];
        gates[r*GSTR + (4+gi)*8 + c] = run * inv;
      }
    }
    __syncthreads();

    // ---- 9. elementwise update; publish Hbf; flag ----
    float hv[2], cv2[2];
    const int er = tid >> 2, ec0 = (tid & 3)*2;
    {
      const float* g = gates + er*GSTR;
      #pragma unroll
      for (int u = 0; u < 2; ++u) {
        const int c = ec0 + u;
        const float ft = g[c];
        const float it = g[8 + c];
        const float ot = g[16 + c];
        const float ch = g[24 + c];
        const float mf = g[32 + c];
        const float mi = g[40 + c];
        const float w2 = mf * mi;
        const float fh = ft * w2 + (mf - w2);
        const float ih = it * w2 + (mi - w2);
        const float cn = fh * cst[er*9 + c] + ih * ch;
        cst[er*9 + c] = cn;
        cv2[u] = cn;
        hv[u] = ot * cn;
      }
      const unsigned pk = (unsigned)f2bf(hv[0]) | ((unsigned)f2bf(hv[1]) << 16);
      ATOM_ST((unsigned*)(a.Hbf + ((size_t)((t & 1)*64 + wg))*512 + er*8 + ec0), pk);
    }
    asm volatile("s_waitcnt vmcnt(0)" ::: "memory");
    __syncthreads();
    if (tid == 0) ATOM_ST(&a.flagH[wg], t+1);

    // ---- 10. x(t+1) quarter 1 GEMM (covers h round-trip) ----
    if (tn < S_LEN) {
      load_xf(a, ux, tn, 1, arow, lane, xf);
      gemm_q(xf, wlds, lane, 1, accN);
    }

    // ---- 11. output writes (off critical path) ----
    {
      const int col = wg*8 + ec0;
      *(float2*)(a.out + (size_t)t*32768 + er*512 + col) = make_float2(hv[0], hv[1]);
      if (t == slenl[er] - 1) {
        *(float2*)(a.out + (size_t)OUT_SH + er*512 + col) = make_float2(hv[0], hv[1]);
        *(float2*)(a.out + (size_t)OUT_SC + er*512 + col) = make_float2(cv2[0], cv2[1]);
      }
    }

    accC[0] = accN[0]; accC[1] = accN[1]; accC[2] = accN[2];
  }
}

// ---------------- host ----------------
extern "C" void kernel_launch(void* const* d_in, const int* in_sizes, int n_in,
                              void* d_out, int out_size, void* d_ws, size_t ws_size,
                              hipStream_t stream) {
  char* ws = (char*)d_ws;

  PrepArgs pa;
  for (int q = 0; q < 6; ++q) {
    pa.W[q]   = (const float*)d_in[3 + 2*q];
    pa.bia[q] = (const float*)d_in[4 + 2*q];
  }
  pa.h0       = (const float*)d_in[1];
  pa.WT       = (unsigned short*)(ws + O_WT);
  pa.bias_all = (float*)(ws + O_BIAS);
  pa.Hbf      = (unsigned short*)(ws + O_HBF);
  pa.flagH    = (int*)(ws + O_FLAGH);
  pa.flagP    = (int*)(ws + O_FLAGP);
  prep_kernel<<<3137, 256, 0, stream>>>(pa);

  const bool ux = (ws_size >= WS_FULL);
  if (ux)
    convx_kernel<<<16384, 256, 0, stream>>>((const float*)d_in[0], (unsigned short*)(ws + O_XBF));

  LstmArgs la;
  la.x        = (const float*)d_in[0];
  la.xbf      = ux ? (const unsigned short*)(ws + O_XBF) : nullptr;
  la.c0       = (const float*)d_in[2];
  la.slen     = (const int*)d_in[15];
  la.WT       = pa.WT;
  la.bias_all = pa.bias_all;
  la.Hbf      = pa.Hbf;
  la.flagH    = pa.flagH;
  la.flagP    = pa.flagP;
  la.P        = (float*)(ws + O_P);
  la.out      = (float*)d_out;

  hipFuncSetAttribute(reinterpret_cast<const void*>(lstm_kernel),
                      hipFuncAttributeMaxDynamicSharedMemorySize, SMEM_TOTAL);
  lstm_kernel<<<NWG, 256, SMEM_TOTAL, stream>>>(la);
}